// Round 1
// baseline (66.850 us; speedup 1.0000x reference)
//
#include <hip/hip_runtime.h>
#include <math.h>

// MVAE forward: persistent kernel, manual grid barriers between dependent stages.
// Grid = 64 WGs x 256 thr = 256 waves; one wave per output row per stage.

#define NWG   64
#define BLOCK 256
#define NWAVE (NWG * (BLOCK / 64))   // 256 waves total

// ---- device-global scratch (avoids d_ws sizing/poison concerns) ----
__device__ int   g_cnt[16];          // barrier phase counters (zeroed per call)
__device__ float g_a0[256], g_a1[256], g_a2[256];
__device__ float g_mu[32], g_lv[32], g_z[32];
__device__ float g_g0[256], g_g1[256], g_g2[256], g_gates[6];
__device__ float g_h0[1536], g_h1[1536], g_h2[1536];
__device__ float g_oute[372];

struct P {
  const float *prev, *curr, *eps;
  const float *ew0,*eb0,*ew1,*eb1,*ew2,*eb2;
  const float *muw,*mub,*lvw,*lvb;
  const float *gw0,*gb0,*gw1,*gb1,*gw2,*gb2,*gw3,*gb3;
  const float *xw0,*xb0,*xw1,*xb1,*xw2,*xb2,*xw3,*xb3;
  float* out;
};

__device__ __forceinline__ float wred(float v) {
#pragma unroll
  for (int m = 32; m; m >>= 1) v += __shfl_xor(v, m, 64);
  return v;
}

__device__ __forceinline__ float elu(float x) { return x > 0.f ? x : expm1f(x); }

// device-scope grid barrier, phase-indexed counters (init kernel zeroes them each call)
__device__ __forceinline__ void gridbar(int phase) {
  __syncthreads();
  if (threadIdx.x == 0) {
    __threadfence();                       // flush this WG's stores to coherence point
    atomicAdd(&g_cnt[phase], 1);           // device-scope by default
    while (__hip_atomic_load(&g_cnt[phase], __ATOMIC_RELAXED,
                             __HIP_MEMORY_SCOPE_AGENT) < NWG)
      __builtin_amdgcn_s_sleep(1);
    __threadfence();                       // invalidate stale cache before reads
  }
  __syncthreads();
}

__device__ __forceinline__ float dot256w(const float* w, const float* x, int lane) {
  float s = 0.f;
#pragma unroll
  for (int k = 0; k < 4; ++k) { int j = lane + 64 * k; s += w[j] * x[j]; }
  return wred(s);
}

// gate (256x256 rows) + expert (1536 x 288 rows) middle stage
__device__ __forceinline__ void stage_mid(const float* gw, const float* gb,
                                          const float* gx, float* gy,
                                          const float* xw, const float* xb,
                                          const float* hx, float* hy,
                                          int lane, int wv) {
  for (int r = wv; r < 1792; r += NWAVE) {
    if (r < 256) {
      float s = dot256w(gw + r * 256, gx, lane);
      if (!lane) gy[r] = elu(s + gb[r]);
    } else {
      int q = r - 256; int e = q >> 8;
      const float* wr = xw + q * 288;
      const float* he = hx + (e << 8);
      float s = (lane < 32 ? g_z[lane] : he[lane - 32]) * wr[lane];
#pragma unroll
      for (int k = 1; k < 4; ++k) { int j = lane + 64 * k; s += wr[j] * he[j - 32]; }
      if (lane < 32) s += wr[lane + 256] * he[lane + 224];
      s = wred(s);
      if (!lane) hy[q] = elu(s + xb[q]);
    }
  }
}

__global__ void mvae_init() {
  if (threadIdx.x < 16) g_cnt[threadIdx.x] = 0;
}

__global__ __launch_bounds__(BLOCK, 1) void mvae_main(P p) {
  const int tid  = threadIdx.x;
  const int lane = tid & 63;
  const int wv   = blockIdx.x * (BLOCK / 64) + (tid >> 6);  // 0..255

  // ---- S0: enc0 = elu(W0 @ [prev|curr] + b0), 256 rows x 124 ----
  {
    const int row = wv;
    float xa = (lane < 62) ? p.prev[lane] : p.curr[lane - 62];
    float xb = (lane < 60) ? p.curr[lane + 2] : 0.f;   // x[lane+64] for lane<60
    const float* wr = p.ew0 + row * 124;
    float s = wr[lane] * xa;
    if (lane < 60) s += wr[lane + 64] * xb;
    s = wred(s);
    if (!lane) g_a0[row] = elu(s + p.eb0[row]);
  }
  gridbar(0);

  // ---- S1: enc1, 256x256 ----
  {
    float s = dot256w(p.ew1 + wv * 256, g_a0, lane);
    if (!lane) g_a1[wv] = elu(s + p.eb1[wv]);
  }
  gridbar(1);

  // ---- S2: enc2, 256x256 ----
  {
    float s = dot256w(p.ew2 + wv * 256, g_a1, lane);
    if (!lane) g_a2[wv] = elu(s + p.eb2[wv]);
  }
  gridbar(2);

  // ---- S3: mu (32x256) and logvar (32x256); write straight to d_out too ----
  if (wv < 64) {
    if (wv < 32) {
      float s = dot256w(p.muw + wv * 256, g_a2, lane);
      if (!lane) { float v = s + p.mub[wv]; g_mu[wv] = v; p.out[62 + wv] = v; }
    } else {
      int r = wv - 32;
      float s = dot256w(p.lvw + r * 256, g_a2, lane);
      if (!lane) { float v = s + p.lvb[r]; g_lv[r] = v; p.out[94 + r] = v; }
    }
  }
  gridbar(3);

  // ---- S4: gate0 (256 rows) + expert h0 (1536 rows), both L=94, x = [z|prev] ----
  {
    // z computed in-register from mu/lv/eps; wave 0 also publishes it for later stages
    float xa = (lane < 32) ? (g_mu[lane] + p.eps[lane] * expf(0.5f * g_lv[lane]))
                           : p.prev[lane - 32];
    float xb = (lane < 30) ? p.prev[lane + 32] : 0.f;  // x[lane+64] in [64,94)
    if (wv == 0 && lane < 32) g_z[lane] = xa;
    for (int r = wv; r < 1792; r += NWAVE) {
      const float* wr; float b; float* dst;
      if (r < 256) { wr = p.gw0 + r * 94; b = p.gb0[r]; dst = g_g0 + r; }
      else { int q = r - 256; wr = p.xw0 + q * 94; b = p.xb0[q]; dst = g_h0 + q; }
      float s = wr[lane] * xa;
      if (lane < 30) s += wr[lane + 64] * xb;
      s = wred(s);
      if (!lane) *dst = elu(s + b);
    }
  }
  gridbar(4);

  // ---- S5: gate1 + expert h1 ----
  stage_mid(p.gw1, p.gb1, g_g0, g_g1, p.xw1, p.xb1, g_h0, g_h1, lane, wv);
  gridbar(5);

  // ---- S6: gate2 + expert h2 ----
  stage_mid(p.gw2, p.gb2, g_g1, g_g2, p.xw2, p.xb2, g_h1, g_h2, lane, wv);
  gridbar(6);

  // ---- S7: gate3 (6 rows x 256, raw logits) + out_e (372 rows x 288) ----
  {
    for (int r = wv; r < 378; r += NWAVE) {
      if (r < 6) {
        float s = dot256w(p.gw3 + r * 256, g_g2, lane);
        if (!lane) g_gates[r] = s + p.gb3[r];
      } else {
        int q = r - 6;            // 0..371 = e*62 + o
        int e = q / 62;
        const float* wr = p.xw3 + q * 288;
        const float* he = g_h2 + (e << 8);
        float s = (lane < 32 ? g_z[lane] : he[lane - 32]) * wr[lane];
#pragma unroll
        for (int k = 1; k < 4; ++k) { int j = lane + 64 * k; s += wr[j] * he[j - 32]; }
        if (lane < 32) s += wr[lane + 256] * he[lane + 224];
        s = wred(s);
        if (!lane) g_oute[q] = s + p.xb3[q];
      }
    }
  }
  gridbar(7);

  // ---- S8: decoded[62] = sum_e out_e * gates[e] ----
  if (blockIdx.x == 0 && tid < 62) {
    float s = 0.f;
#pragma unroll
    for (int e = 0; e < 6; ++e) s += g_oute[e * 62 + tid] * g_gates[e];
    p.out[tid] = s;
  }
}

extern "C" void kernel_launch(void* const* d_in, const int* in_sizes, int n_in,
                              void* d_out, int out_size, void* d_ws, size_t ws_size,
                              hipStream_t stream) {
  (void)in_sizes; (void)n_in; (void)d_ws; (void)ws_size; (void)out_size;
  const float* const* in = (const float* const*)d_in;
  P p;
  p.prev = in[0];  p.curr = in[1];  p.eps = in[2];
  p.ew0 = in[3];   p.eb0 = in[4];   p.ew1 = in[5];  p.eb1 = in[6];
  p.ew2 = in[7];   p.eb2 = in[8];
  p.muw = in[9];   p.mub = in[10];  p.lvw = in[11]; p.lvb = in[12];
  p.gw0 = in[13];  p.gb0 = in[14];  p.gw1 = in[15]; p.gb1 = in[16];
  p.gw2 = in[17];  p.gb2 = in[18];  p.gw3 = in[19]; p.gb3 = in[20];
  p.xw0 = in[21];  p.xb0 = in[22];  p.xw1 = in[23]; p.xb1 = in[24];
  p.xw2 = in[25];  p.xb2 = in[26];  p.xw3 = in[27]; p.xb3 = in[28];
  p.out = (float*)d_out;

  mvae_init<<<1, 64, 0, stream>>>();
  mvae_main<<<NWG, BLOCK, 0, stream>>>(p);
}